// Round 1
// baseline (898.958 us; speedup 1.0000x reference)
//
#include <hip/hip_runtime.h>
#include <cstdint>

// Shapes fixed by setup_inputs(): B=8, SQ=SKV=16, H=16, D=128, CACHE=8192.
#define B_     8
#define SQ_    16
#define SKV_   16
#define H_     16
#define D_     128
#define CACHE_ 8192
#define TK     64   // keys per tile

typedef __attribute__((ext_vector_type(8))) short bf16x8;
typedef __attribute__((ext_vector_type(4))) float f32x4;

__device__ __forceinline__ unsigned short f2bf(float x) {
  union { float f; unsigned u; } v; v.f = x;
  unsigned r = v.u + 0x7FFFu + ((v.u >> 16) & 1u);  // RNE
  return (unsigned short)(r >> 16);
}

// Flash attention over key range [k0,k1) for one (b,h); optional split partials.
__global__ __launch_bounds__(256, 2) void attn_partial(
    const float* __restrict__ q, const float* __restrict__ knew,
    const float* __restrict__ vnew, const float* __restrict__ kcache,
    const float* __restrict__ vcache, const int* __restrict__ sidx_p,
    float* __restrict__ o_part, float* __restrict__ m_part,
    float* __restrict__ l_part, float* __restrict__ out,
    int S, int final_mode)
{
  // LDS: pads chosen for bank behavior + 16B alignment of b128 frag reads
  __shared__ unsigned short q_bf[16][136];   // 272B row stride (16-aligned)
  __shared__ unsigned short k_bf[TK][136];
  __shared__ unsigned short v_bf[TK][136];
  __shared__ float          s_tile[16][68];
  __shared__ unsigned short p_bf[16][80];    // 160B stride (16-aligned)
  __shared__ float m_arr[16], l_arr[16], a_arr[16];

  const int t  = threadIdx.x;
  const int bh = blockIdx.x;
  const int sp = blockIdx.y;
  const int b  = bh >> 4, h = bh & 15;
  const int sidx = *sidx_p;
  const int L = sidx + SKV_;
  const int chunk = (L + S - 1) / S;
  const int k0 = sp * chunk;
  const int k1 = min(k0 + chunk, L);

  if (t < 16) { m_arr[t] = -1e30f; l_arr[t] = 0.f; }

  // Load Q tile (16 x 128) -> bf16 LDS
  {
    int i = t >> 4, c = (t & 15) * 8;
    const float4* qp = (const float4*)(q + ((((long)b * SQ_ + i) * H_ + h) * D_ + c));
    float4 a0 = qp[0], a1 = qp[1];
    ushort4 u0 = make_ushort4(f2bf(a0.x), f2bf(a0.y), f2bf(a0.z), f2bf(a0.w));
    ushort4 u1 = make_ushort4(f2bf(a1.x), f2bf(a1.y), f2bf(a1.z), f2bf(a1.w));
    *(ushort4*)&q_bf[i][c]     = u0;
    *(ushort4*)&q_bf[i][c + 4] = u1;
  }
  __syncthreads();

  const int lane = t & 63;
  const int w    = t >> 6;      // wave 0..3
  const int m    = lane & 15;
  const int qd   = lane >> 4;   // quad 0..3

  // Persistent Q A-fragments: A[m=lane&15][k=quad*8+j], k blocks of 32
  bf16x8 qa[4];
  #pragma unroll
  for (int kb = 0; kb < 4; ++kb)
    qa[kb] = *(const bf16x8*)&q_bf[m][kb * 32 + qd * 8];

  f32x4 acc0 = {0.f, 0.f, 0.f, 0.f};   // out cols w*32 + m
  f32x4 acc1 = {0.f, 0.f, 0.f, 0.f};   // out cols w*32 + 16 + m
  const float scale = 0.08838834764831845f;  // 1/sqrt(128)

  for (int kt = k0; kt < k1; kt += TK) {
    __syncthreads();  // previous tile's LDS fully consumed
    // ---- stage K/V tile (fp32 global -> bf16 LDS), zeros past k1 ----
    #pragma unroll
    for (int pass = 0; pass < 8; ++pass) {
      int r = pass * 8 + (t >> 5);
      int c = (t & 31) * 4;
      int l = kt + r;
      float4 kv = make_float4(0.f, 0.f, 0.f, 0.f);
      float4 vv = make_float4(0.f, 0.f, 0.f, 0.f);
      if (l < k1) {
        const float *kp, *vp;
        if (l < sidx) {
          long off = (((long)b * CACHE_ + l) * H_ + h) * (long)D_ + c;
          kp = kcache + off; vp = vcache + off;
        } else {
          long off = (((long)b * SKV_ + (l - sidx)) * H_ + h) * (long)D_ + c;
          kp = knew + off; vp = vnew + off;
        }
        kv = *(const float4*)kp;
        vv = *(const float4*)vp;
      }
      *(ushort4*)&k_bf[r][c] = make_ushort4(f2bf(kv.x), f2bf(kv.y), f2bf(kv.z), f2bf(kv.w));
      *(ushort4*)&v_bf[r][c] = make_ushort4(f2bf(vv.x), f2bf(vv.y), f2bf(vv.z), f2bf(vv.w));
    }
    __syncthreads();

    // ---- S = Q K^T (wave w owns key cols w*16..w*16+15) ----
    f32x4 sc = {0.f, 0.f, 0.f, 0.f};
    #pragma unroll
    for (int kb = 0; kb < 4; ++kb) {
      bf16x8 kfrag = *(const bf16x8*)&k_bf[w * 16 + m][kb * 32 + qd * 8]; // B[k=d][n=key]
      sc = __builtin_amdgcn_mfma_f32_16x16x32_bf16(qa[kb], kfrag, sc, 0, 0, 0);
    }
    #pragma unroll
    for (int reg = 0; reg < 4; ++reg)
      s_tile[qd * 4 + reg][w * 16 + m] = sc[reg] * scale;  // C: row=quad*4+reg, col=lane&15
    __syncthreads();

    // ---- online softmax (16 lanes per q-row) ----
    {
      int r = t >> 4, c4 = t & 15;
      float sv[4];
      #pragma unroll
      for (int kk = 0; kk < 4; ++kk) {
        int col = c4 + kk * 16;
        float x = s_tile[r][col];
        sv[kk] = (kt + col < k1) ? x : -1e30f;
      }
      float tmax = fmaxf(fmaxf(sv[0], sv[1]), fmaxf(sv[2], sv[3]));
      #pragma unroll
      for (int d = 1; d < 16; d <<= 1)
        tmax = fmaxf(tmax, __shfl_xor(tmax, d, 16));
      float mold = m_arr[r];
      float mnew = fmaxf(mold, tmax);
      float alpha = __expf(mold - mnew);
      float tsum = 0.f;
      #pragma unroll
      for (int kk = 0; kk < 4; ++kk) {
        float p = __expf(sv[kk] - mnew);   // OOB cols -> exactly 0
        tsum += p;
        p_bf[r][c4 + kk * 16] = f2bf(p);
      }
      #pragma unroll
      for (int d = 1; d < 16; d <<= 1)
        tsum += __shfl_xor(tsum, d, 16);
      if (c4 == 0) {
        l_arr[r] = l_arr[r] * alpha + tsum;
        m_arr[r] = mnew;
        a_arr[r] = alpha;
      }
    }
    __syncthreads();

    // ---- rescale accumulators, then O += P V (wave w owns d-cols w*32..+31) ----
    #pragma unroll
    for (int reg = 0; reg < 4; ++reg) {
      float a = a_arr[qd * 4 + reg];
      acc0[reg] *= a; acc1[reg] *= a;
    }
    #pragma unroll
    for (int kc = 0; kc < 2; ++kc) {
      bf16x8 pa = *(const bf16x8*)&p_bf[m][kc * 32 + qd * 8];  // A[m=q][k=key]
      bf16x8 vb0, vb1;
      #pragma unroll
      for (int j = 0; j < 8; ++j) {
        int row = kc * 32 + qd * 8 + j;                         // B[k=key][n=dcol]
        vb0[j] = (short)v_bf[row][w * 32 + m];
        vb1[j] = (short)v_bf[row][w * 32 + 16 + m];
      }
      acc0 = __builtin_amdgcn_mfma_f32_16x16x32_bf16(pa, vb0, acc0, 0, 0, 0);
      acc1 = __builtin_amdgcn_mfma_f32_16x16x32_bf16(pa, vb1, acc1, 0, 0, 0);
    }
  }

  // ---- epilogue ----
  if (final_mode) {
    #pragma unroll
    for (int reg = 0; reg < 4; ++reg) {
      int row = qd * 4 + reg;
      float inv = 1.0f / l_arr[row];
      long o0 = (((long)b * SQ_ + row) * H_ + h) * (long)D_ + w * 32 + m;
      out[o0]      = acc0[reg] * inv;
      out[o0 + 16] = acc1[reg] * inv;
    }
  } else {
    long base = ((long)bh * S + sp) * 16;
    #pragma unroll
    for (int reg = 0; reg < 4; ++reg) {
      int row = qd * 4 + reg;
      long o0 = (base + row) * 128 + w * 32 + m;
      o_part[o0]      = acc0[reg];
      o_part[o0 + 16] = acc1[reg];
    }
    if (t < 16) {
      m_part[base + t] = m_arr[t];
      l_part[base + t] = l_arr[t];
    }
  }
}

__global__ void attn_combine(const float* __restrict__ o_part,
                             const float* __restrict__ m_part,
                             const float* __restrict__ l_part,
                             float* __restrict__ out, int S)
{
  int row = blockIdx.x;            // bh*16 + i
  int bh = row >> 4, i = row & 15;
  int b = bh >> 4, h = bh & 15;
  int d = threadIdx.x;             // 0..127
  float mg = -1e30f;
  for (int s = 0; s < S; ++s)
    mg = fmaxf(mg, m_part[((long)bh * S + s) * 16 + i]);
  float num = 0.f, den = 0.f;
  for (int s = 0; s < S; ++s) {
    long pi = ((long)bh * S + s) * 16 + i;
    float ws = __expf(m_part[pi] - mg);
    den += ws * l_part[pi];
    num += ws * o_part[pi * 128 + d];
  }
  out[(((long)b * SQ_ + i) * H_ + h) * (long)D_ + d] = num / den;
}

extern "C" void kernel_launch(void* const* d_in, const int* in_sizes, int n_in,
                              void* d_out, int out_size, void* d_ws, size_t ws_size,
                              hipStream_t stream)
{
  const float* q  = (const float*)d_in[0];
  const float* k  = (const float*)d_in[1];
  const float* v  = (const float*)d_in[2];
  const float* kc = (const float*)d_in[3];
  const float* vc = (const float*)d_in[4];
  const int* sidx = (const int*)d_in[5];
  float* out = (float*)d_out;

  const int S = 4;
  const size_t need = (size_t)S * B_ * H_ * (16 * 128 + 32) * sizeof(float);
  if (ws_size >= need) {
    float* o_part = (float*)d_ws;
    float* m_part = o_part + (size_t)S * B_ * H_ * 16 * 128;
    float* l_part = m_part + (size_t)S * B_ * H_ * 16;
    attn_partial<<<dim3(B_ * H_, S), 256, 0, stream>>>(
        q, k, v, kc, vc, sidx, o_part, m_part, l_part, out, S, 0);
    attn_combine<<<dim3(B_ * H_ * SQ_), 128, 0, stream>>>(
        o_part, m_part, l_part, out, S);
  } else {
    attn_partial<<<dim3(B_ * H_, 1), 256, 0, stream>>>(
        q, k, v, kc, vc, sidx, nullptr, nullptr, nullptr, out, 1, 1);
  }
}

// Round 2
// 880.548 us; speedup vs baseline: 1.0209x; 1.0209x over previous
//
#include <hip/hip_runtime.h>
#include <cstdint>

// Shapes fixed by setup_inputs(): B=8, SQ=SKV=16, H=16, D=128, CACHE=8192.
#define B_     8
#define SQ_    16
#define SKV_   16
#define H_     16
#define D_     128
#define CACHE_ 8192
#define TK     64   // keys per tile
#define NSPLIT 6    // 128 bh * 6 = 768 blocks = 3 blocks/CU on 256 CUs

typedef __attribute__((ext_vector_type(8))) short bf16x8;
typedef __attribute__((ext_vector_type(4))) float f32x4;

__device__ __forceinline__ unsigned short f2bf(float x) {
  union { float f; unsigned u; } v; v.f = x;
  unsigned r = v.u + 0x7FFFu + ((v.u >> 16) & 1u);  // RNE
  return (unsigned short)(r >> 16);
}

// Flash attention over key range [k0,k1) for one (b,h); optional split partials.
// launch_bounds(256,3): 3 waves/EU -> 3 blocks/CU (LDS 46.8 KB/block fits 3x).
__global__ __launch_bounds__(256, 3) void attn_partial(
    const float* __restrict__ q, const float* __restrict__ knew,
    const float* __restrict__ vnew, const float* __restrict__ kcache,
    const float* __restrict__ vcache, const int* __restrict__ sidx_p,
    float* __restrict__ o_part, float* __restrict__ m_part,
    float* __restrict__ l_part, float* __restrict__ out,
    int S, int final_mode)
{
  // K stride 136 shorts (272 B, 16B-aligned rows for ds_read_b128 frags).
  // V stride 140 shorts: 8-row step = 560 words = 16 mod 32 banks -> the
  // PV ds_read_u16 gather degrades from 4-way to free 2-way conflict.
  __shared__ unsigned short q_bf[16][136];
  __shared__ unsigned short k_bf[TK][136];
  __shared__ unsigned short v_bf[TK][140];
  __shared__ float          s_tile[16][68];
  __shared__ unsigned short p_bf[16][80];
  __shared__ float m_arr[16], l_arr[16], a_arr[16];

  const int t  = threadIdx.x;
  const int bh = blockIdx.x;
  const int sp = blockIdx.y;
  const int b  = bh >> 4, h = bh & 15;
  const int sidx = *sidx_p;
  const int L = sidx + SKV_;
  const int chunk = (L + S - 1) / S;
  const int k0 = sp * chunk;
  const int k1 = min(k0 + chunk, L);

  if (t < 16) { m_arr[t] = -1e30f; l_arr[t] = 0.f; }

  // Load Q tile (16 x 128) -> bf16 LDS
  {
    int i = t >> 4, c = (t & 15) * 8;
    const float4* qp = (const float4*)(q + ((((long)b * SQ_ + i) * H_ + h) * D_ + c));
    float4 a0 = qp[0], a1 = qp[1];
    ushort4 u0 = make_ushort4(f2bf(a0.x), f2bf(a0.y), f2bf(a0.z), f2bf(a0.w));
    ushort4 u1 = make_ushort4(f2bf(a1.x), f2bf(a1.y), f2bf(a1.z), f2bf(a1.w));
    *(ushort4*)&q_bf[i][c]     = u0;
    *(ushort4*)&q_bf[i][c + 4] = u1;
  }
  __syncthreads();

  const int lane = t & 63;
  const int w    = t >> 6;      // wave 0..3
  const int m    = lane & 15;
  const int qd   = lane >> 4;   // quad 0..3

  // Persistent Q A-fragments: A[m=lane&15][k=quad*8+j], k blocks of 32
  bf16x8 qa[4];
  #pragma unroll
  for (int kb = 0; kb < 4; ++kb)
    qa[kb] = *(const bf16x8*)&q_bf[m][kb * 32 + qd * 8];

  f32x4 acc0 = {0.f, 0.f, 0.f, 0.f};   // out cols w*32 + m
  f32x4 acc1 = {0.f, 0.f, 0.f, 0.f};   // out cols w*32 + 16 + m
  const float scale = 0.08838834764831845f;  // 1/sqrt(128)

  for (int kt = k0; kt < k1; kt += TK) {
    __syncthreads();  // previous tile's LDS fully consumed
    // ---- stage K/V tile (fp32 global -> bf16 LDS), zeros past k1 ----
    #pragma unroll
    for (int pass = 0; pass < 8; ++pass) {
      int r = pass * 8 + (t >> 5);
      int c = (t & 31) * 4;
      int l = kt + r;
      float4 kv = make_float4(0.f, 0.f, 0.f, 0.f);
      float4 vv = make_float4(0.f, 0.f, 0.f, 0.f);
      if (l < k1) {
        const float *kp, *vp;
        if (l < sidx) {
          long off = (((long)b * CACHE_ + l) * H_ + h) * (long)D_ + c;
          kp = kcache + off; vp = vcache + off;
        } else {
          long off = (((long)b * SKV_ + (l - sidx)) * H_ + h) * (long)D_ + c;
          kp = knew + off; vp = vnew + off;
        }
        kv = *(const float4*)kp;
        vv = *(const float4*)vp;
      }
      *(ushort4*)&k_bf[r][c] = make_ushort4(f2bf(kv.x), f2bf(kv.y), f2bf(kv.z), f2bf(kv.w));
      *(ushort4*)&v_bf[r][c] = make_ushort4(f2bf(vv.x), f2bf(vv.y), f2bf(vv.z), f2bf(vv.w));
    }
    __syncthreads();

    // ---- S = Q K^T (wave w owns key cols w*16..w*16+15) ----
    f32x4 sc = {0.f, 0.f, 0.f, 0.f};
    #pragma unroll
    for (int kb = 0; kb < 4; ++kb) {
      bf16x8 kfrag = *(const bf16x8*)&k_bf[w * 16 + m][kb * 32 + qd * 8]; // B[k=d][n=key]
      sc = __builtin_amdgcn_mfma_f32_16x16x32_bf16(qa[kb], kfrag, sc, 0, 0, 0);
    }
    #pragma unroll
    for (int reg = 0; reg < 4; ++reg)
      s_tile[qd * 4 + reg][w * 16 + m] = sc[reg] * scale;  // C: row=quad*4+reg, col=lane&15
    __syncthreads();

    // ---- online softmax (16 lanes per q-row) ----
    {
      int r = t >> 4, c4 = t & 15;
      float sv[4];
      #pragma unroll
      for (int kk = 0; kk < 4; ++kk) {
        int col = c4 + kk * 16;
        float x = s_tile[r][col];
        sv[kk] = (kt + col < k1) ? x : -1e30f;
      }
      float tmax = fmaxf(fmaxf(sv[0], sv[1]), fmaxf(sv[2], sv[3]));
      #pragma unroll
      for (int d = 1; d < 16; d <<= 1)
        tmax = fmaxf(tmax, __shfl_xor(tmax, d, 16));
      float mold = m_arr[r];
      float mnew = fmaxf(mold, tmax);
      float alpha = __expf(mold - mnew);
      float tsum = 0.f;
      #pragma unroll
      for (int kk = 0; kk < 4; ++kk) {
        float p = __expf(sv[kk] - mnew);   // OOB cols -> exactly 0
        tsum += p;
        p_bf[r][c4 + kk * 16] = f2bf(p);
      }
      #pragma unroll
      for (int d = 1; d < 16; d <<= 1)
        tsum += __shfl_xor(tsum, d, 16);
      if (c4 == 0) {
        l_arr[r] = l_arr[r] * alpha + tsum;
        m_arr[r] = mnew;
        a_arr[r] = alpha;
      }
    }
    __syncthreads();

    // ---- rescale accumulators, then O += P V (wave w owns d-cols w*32..+31) ----
    #pragma unroll
    for (int reg = 0; reg < 4; ++reg) {
      float a = a_arr[qd * 4 + reg];
      acc0[reg] *= a; acc1[reg] *= a;
    }
    #pragma unroll
    for (int kc = 0; kc < 2; ++kc) {
      bf16x8 pa = *(const bf16x8*)&p_bf[m][kc * 32 + qd * 8];  // A[m=q][k=key]
      bf16x8 vb0, vb1;
      #pragma unroll
      for (int j = 0; j < 8; ++j) {
        int row = kc * 32 + qd * 8 + j;                         // B[k=key][n=dcol]
        vb0[j] = (short)v_bf[row][w * 32 + m];
        vb1[j] = (short)v_bf[row][w * 32 + 16 + m];
      }
      acc0 = __builtin_amdgcn_mfma_f32_16x16x32_bf16(pa, vb0, acc0, 0, 0, 0);
      acc1 = __builtin_amdgcn_mfma_f32_16x16x32_bf16(pa, vb1, acc1, 0, 0, 0);
    }
  }

  // ---- epilogue ----
  if (final_mode) {
    #pragma unroll
    for (int reg = 0; reg < 4; ++reg) {
      int row = qd * 4 + reg;
      float inv = 1.0f / l_arr[row];
      long o0 = (((long)b * SQ_ + row) * H_ + h) * (long)D_ + w * 32 + m;
      out[o0]      = acc0[reg] * inv;
      out[o0 + 16] = acc1[reg] * inv;
    }
  } else {
    long base = ((long)bh * S + sp) * 16;
    #pragma unroll
    for (int reg = 0; reg < 4; ++reg) {
      int row = qd * 4 + reg;
      long o0 = (base + row) * 128 + w * 32 + m;
      o_part[o0]      = acc0[reg];
      o_part[o0 + 16] = acc1[reg];
    }
    if (t < 16) {
      m_part[base + t] = m_arr[t];
      l_part[base + t] = l_arr[t];
    }
  }
}

__global__ void attn_combine(const float* __restrict__ o_part,
                             const float* __restrict__ m_part,
                             const float* __restrict__ l_part,
                             float* __restrict__ out, int S)
{
  int row = blockIdx.x;            // bh*16 + i
  int bh = row >> 4, i = row & 15;
  int b = bh >> 4, h = bh & 15;
  int d = threadIdx.x;             // 0..127
  float mg = -1e30f;
  for (int s = 0; s < S; ++s)
    mg = fmaxf(mg, m_part[((long)bh * S + s) * 16 + i]);
  float num = 0.f, den = 0.f;
  for (int s = 0; s < S; ++s) {
    long pi = ((long)bh * S + s) * 16 + i;
    float ws = __expf(m_part[pi] - mg);
    den += ws * l_part[pi];
    num += ws * o_part[pi * 128 + d];
  }
  out[(((long)b * SQ_ + i) * H_ + h) * (long)D_ + d] = num / den;
}

extern "C" void kernel_launch(void* const* d_in, const int* in_sizes, int n_in,
                              void* d_out, int out_size, void* d_ws, size_t ws_size,
                              hipStream_t stream)
{
  const float* q  = (const float*)d_in[0];
  const float* k  = (const float*)d_in[1];
  const float* v  = (const float*)d_in[2];
  const float* kc = (const float*)d_in[3];
  const float* vc = (const float*)d_in[4];
  const int* sidx = (const int*)d_in[5];
  float* out = (float*)d_out;

  const int S = NSPLIT;
  const size_t need = (size_t)S * B_ * H_ * (16 * 128 + 32) * sizeof(float);
  if (ws_size >= need) {
    float* o_part = (float*)d_ws;
    float* m_part = o_part + (size_t)S * B_ * H_ * 16 * 128;
    float* l_part = m_part + (size_t)S * B_ * H_ * 16;
    attn_partial<<<dim3(B_ * H_, S), 256, 0, stream>>>(
        q, k, v, kc, vc, sidx, o_part, m_part, l_part, out, S, 0);
    attn_combine<<<dim3(B_ * H_ * SQ_), 128, 0, stream>>>(
        o_part, m_part, l_part, out, S);
  } else {
    attn_partial<<<dim3(B_ * H_, 1), 256, 0, stream>>>(
        q, k, v, kc, vc, sidx, nullptr, nullptr, nullptr, out, 1, 1);
  }
}